// Round 5
// baseline (156.855 us; speedup 1.0000x reference)
//
#include <hip/hip_runtime.h>
#include <hip/hip_bf16.h>
#include <cmath>

#define DIM 128
#define HEADS 8
#define NBATCH 2
#define NQ 6400   /* 80*80 */
#define NKV 1600  /* 40*40 */
#define NC 50     /* kv chunks of 32 */
#define NSPLIT 2  /* kv-split count */
#define CPS 25    /* chunks per split */
#define BN_EPS 1e-5f
#define LOG2E 1.4426950408889634f

typedef __bf16 bf16_t;
typedef __attribute__((ext_vector_type(8))) __bf16 bf16x8;
typedef __attribute__((ext_vector_type(16))) float f32x16;

union BF8U { bf16x8 v; unsigned u[4]; };

// pack two f32 -> packed bf16 (a->lo, b->hi); lowers to v_cvt_pk_bf16_f32 (RNE)
__device__ inline unsigned packbf2(float a, float b) {
  union { __hip_bfloat162 v; unsigned u; } r;
  r.v = __float22bfloat162_rn(make_float2(a, b));
  return r.u;
}

__device__ inline unsigned short f2bf(float v) {
  unsigned u = __float_as_uint(v);
  return (unsigned short)((u + 0x7FFFu + ((u >> 16) & 1u)) >> 16);
}

// ---------------------------------------------------------------------------
// wcast: one-time f32 -> bf16 weight cast (q|k|v|proj|sr -> Wb). 128 blocks.
// ---------------------------------------------------------------------------
__global__ __launch_bounds__(256) void wcast(
    const float* __restrict__ qw, const float* __restrict__ kw,
    const float* __restrict__ vw, const float* __restrict__ pw,
    const float* __restrict__ srw, unsigned short* __restrict__ Wb)
{
  int e4 = (blockIdx.x * 256 + threadIdx.x) * 4;   // 0..131068, step 4
  const float* src; int idx;
  if (e4 < 16384)      { src = qw;  idx = e4; }
  else if (e4 < 32768) { src = kw;  idx = e4 - 16384; }
  else if (e4 < 49152) { src = vw;  idx = e4 - 32768; }
  else if (e4 < 65536) { src = pw;  idx = e4 - 49152; }
  else                 { src = srw; idx = e4 - 65536; }
  float4 v = *(const float4*)(src + idx);
  uint2 wv;
  wv.x = packbf2(v.x, v.y);
  wv.y = packbf2(v.z, v.w);
  *(uint2*)&Wb[e4] = wv;
}

// ---------------------------------------------------------------------------
// Fused q + (sr -> bn -> relu -> k -> v) GEMMs. A-operands staged from f32 x
// into LDS per block (transpose/im2col fused); B-operands bf16 rows of Wb.
// blocks [0,50): sr->k->v. blocks [50,250): q tile. (unchanged)
// ---------------------------------------------------------------------------
__global__ __launch_bounds__(256) void mgemm_qsrkv(
    const float* __restrict__ x, const bf16_t* __restrict__ Wb,
    const float* __restrict__ q_b, const float* __restrict__ sr_b,
    const float* __restrict__ k_b, const float* __restrict__ v_b,
    const float* __restrict__ bng, const float* __restrict__ bnb,
    const float* __restrict__ bnm, const float* __restrict__ bnv,
    unsigned short* __restrict__ Qb,
    unsigned short* __restrict__ Kp, unsigned short* __restrict__ Vp,
    float sl)
{
  __shared__ __align__(16) unsigned short xs4[32][520]; // sr A tile (im2col)
  __shared__ __align__(16) unsigned short xs[32][136];  // relu out / q A tile
  int t = threadIdx.x;
  int ln = t & 31, hf = (t >> 5) & 1, wid = t >> 6;
  int b = blockIdx.y;
  int o = wid * 32 + ln;

  if (blockIdx.x < 50) {             // ---- sr -> k -> v part ----
    int cid = blockIdx.x;
    int s0 = cid * 32;

    // Stage X4 tile: token tx, values (c,ky,kx) in im2col order c*4+ky*2+kx.
    {
      int tx = t & 31, g = t >> 5;
      int s = s0 + tx;
      int i = s / 40, j = s % 40;
      const float* xb = x + (size_t)b * DIM * NQ;
#pragma unroll
      for (int u = 0; u < 32; ++u) {
        int idx2 = g * 32 + u;       // c*2 + ky
        int c = idx2 >> 1, ky = idx2 & 1;
        const float* src = xb + (size_t)c * NQ + (2 * i + ky) * 80 + 2 * j;
        float2 vv = *(const float2*)src;             // kx = 0,1 contiguous
        *(unsigned*)&xs4[tx][c * 4 + ky * 2] = packbf2(vv.x, vv.y);
      }
    }
    __syncthreads();

    // sr GEMM: K = 512 off the LDS tile; B rows from Wb (bf16).
    const unsigned short* arow = &xs4[ln][hf * 8];
    const bf16_t* brow = &Wb[65536 + (size_t)o * 512 + hf * 8];
    f32x16 acc = {};
#pragma unroll 8
    for (int c0 = 0; c0 < 512; c0 += 16) {
      bf16x8 af = *(const bf16x8*)&arow[c0];
      bf16x8 bf = *(const bf16x8*)&brow[c0];
      acc = __builtin_amdgcn_mfma_f32_32x32x16_bf16(af, bf, acc, 0, 0, 0);
    }
    float bv = sr_b[o];
    float inv = bng[o] / sqrtf(bnv[o] + BN_EPS);
    float b2 = bnb[o] - bnm[o] * inv;
#pragma unroll
    for (int g = 0; g < 4; ++g)
#pragma unroll
      for (int jj = 0; jj < 4; ++jj) {
        int sr = 8 * g + 4 * hf + jj;
        xs[sr][o] = f2bf(fmaxf((acc[4 * g + jj] + bv) * inv + b2, 0.f));
      }
    __syncthreads();

    // k + v GEMMs (C=128) off the LDS tile, bf16 weight rows
    const unsigned short* ar2 = &xs[ln][hf * 8];
    const bf16_t* kbrow = &Wb[16384 + (size_t)o * DIM + hf * 8];
    const bf16_t* vbrow = &Wb[32768 + (size_t)o * DIM + hf * 8];
    f32x16 ka = {}, va = {};
#pragma unroll
    for (int c0 = 0; c0 < 128; c0 += 16) {
      bf16x8 af = *(const bf16x8*)&ar2[c0];
      bf16x8 kb = *(const bf16x8*)&kbrow[c0];
      bf16x8 vb = *(const bf16x8*)&vbrow[c0];
      ka = __builtin_amdgcn_mfma_f32_32x32x16_bf16(af, kb, ka, 0, 0, 0);
      va = __builtin_amdgcn_mfma_f32_32x32x16_bf16(af, vb, va, 0, 0, 0);
    }
    int hloc = o >> 4, d = o & 15;
    {
      float kb2 = k_b[o];
      size_t CB = (((size_t)b * HEADS + hloc) * NC + cid) * 512;
#pragma unroll
      for (int g = 0; g < 4; ++g)
#pragma unroll
        for (int jj = 0; jj < 4; ++jj) {
          int sl2 = 8 * g + 4 * hf + jj;
          Kp[CB + sl2 * 16 + d] = f2bf(ka[4 * g + jj] + kb2);
        }
    }
    {
      float vb2 = v_b[o];
      size_t CB = (((size_t)b * HEADS + hloc) * NC + cid) * 1024;
      uint4 w0, w1;
      w0.x = packbf2(va[0] + vb2, va[1] + vb2);
      w0.y = packbf2(va[2] + vb2, va[3] + vb2);
      w0.z = packbf2(va[4] + vb2, va[5] + vb2);
      w0.w = packbf2(va[6] + vb2, va[7] + vb2);
      w1.x = packbf2(va[8] + vb2, va[9] + vb2);
      w1.y = packbf2(va[10] + vb2, va[11] + vb2);
      w1.z = packbf2(va[12] + vb2, va[13] + vb2);
      w1.w = packbf2(va[14] + vb2, va[15] + vb2);
      *(uint4*)&Vp[CB + d * 16 + hf * 8] = w0;       // va block
      *(uint4*)&Vp[CB + 512 + d * 16 + hf * 8] = w1; // vb block
    }
    // Vp lane-16 (denominator) rows for this (b, chunk), all 8 heads
    {
      int hh = t >> 5, pos = t & 31;
      size_t addr = (((size_t)b * HEADS + hh) * NC + cid) * 1024 + 256 +
                    ((pos & 16) ? 512 : 0) + (pos & 15);
      Vp[addr] = 0x3F80;               // 1.0 bf16
    }
  } else {                           // ---- q part (C = 128) ----
    int s0 = (blockIdx.x - 50) * 32;

    // Stage 32-token x 128-channel bf16 tile, token-major (coalesced reads).
    {
      int tx = t & 31, cg = t >> 5;
      const float* xb = x + (size_t)b * DIM * NQ + s0 + tx;
#pragma unroll
      for (int it = 0; it < 8; ++it) {
        int c = 2 * cg + 16 * it;
        float a0 = xb[(size_t)c * NQ];
        float a1 = xb[(size_t)(c + 1) * NQ];
        *(unsigned*)&xs[tx][c] = packbf2(a0, a1);
      }
    }
    __syncthreads();

    const unsigned short* arow = &xs[ln][hf * 8];
    const bf16_t* brow = &Wb[(size_t)o * DIM + hf * 8];
    f32x16 acc = {};
#pragma unroll
    for (int c0 = 0; c0 < 128; c0 += 16) {
      bf16x8 af = *(const bf16x8*)&arow[c0];
      bf16x8 bf = *(const bf16x8*)&brow[c0];
      acc = __builtin_amdgcn_mfma_f32_32x32x16_bf16(af, bf, acc, 0, 0, 0);
    }
    float bv = q_b[o];
#pragma unroll
    for (int g = 0; g < 4; ++g)
#pragma unroll
      for (int jj = 0; jj < 4; ++jj) {
        int sq = s0 + 8 * g + 4 * hf + jj;
        Qb[((size_t)b * NQ + sq) * DIM + o] = f2bf((acc[4 * g + jj] + bv) * sl);
      }
  }
}

// ---------------------------------------------------------------------------
// MFMA attention, LDS-staged K/V (round-5). Diagnosis from rounds 2-4: each
// wave-iter cost ~1500 cyc — exposed L2 latency (true prefetch distance was
// 1 iter) + 4x redundant per-wave K/V loads + register-rotation waitcnts.
// Fix: all 4 waves of a block share one (b,h,split) K/V stream; each 3 KB
// chunk is staged ONCE per block into double-buffered LDS via cooperative
// reg-staged loads (T14: global loads issued at iter start, ds_write after
// compute, single barrier per iter). Waves read fragments with ds_read_b128
// (64 lanes cover the chunk contiguously -> conflict-free). VGPR ~90 ->
// >=5 waves/SIMD cap; at NSPLIT=2 (1600 blocks, 6.25/CU) demand ~fully
// resident. grid (50, 8, 4): z = b + 2*split. block 256.
// ---------------------------------------------------------------------------
__global__ __launch_bounds__(256) void attn_split(
    const bf16_t* __restrict__ Qb, const bf16_t* __restrict__ Kp,
    const bf16_t* __restrict__ Vp, unsigned short* __restrict__ Pb,
    float* __restrict__ Lsum)
{
  __shared__ __align__(16) unsigned short ldsK[2][512];
  __shared__ __align__(16) unsigned short ldsV[2][1024];

  const int t = threadIdx.x;
  const int ln = t & 31, hf = (t >> 5) & 1, wid = t >> 6;
  const int h = blockIdx.y;
  const int b = blockIdx.z & 1, sp = blockIdx.z >> 1;
  const int q0 = blockIdx.x * 128 + wid * 32;

  bf16x8 qf = *(const bf16x8*)&Qb[((size_t)b * NQ + q0 + ln) * DIM + h * 16 + hf * 8];
  const int bh = b * HEADS + h;
  const bf16_t* kcg = &Kp[((size_t)bh * NC + sp * CPS) * 512];
  const bf16_t* vcg = &Vp[((size_t)bh * NC + sp * CPS) * 1024];

  // stage chunk 0
  if (t < 64)       *(uint4*)&ldsK[0][t * 8] = *(const uint4*)&kcg[t * 8];
  else if (t < 192) *(uint4*)&ldsV[0][(t - 64) * 8] = *(const uint4*)&vcg[(t - 64) * 8];
  __syncthreads();

  f32x16 acc0 = {}, acc1 = {};
  const f32x16 zero = {};

  for (int c = 0; c < CPS; ++c) {
    const int cb = c & 1;
    uint4 tmp;
    if (c + 1 < CPS) {               // issue next-chunk loads early (T14)
      if (t < 64)       tmp = *(const uint4*)&kcg[(size_t)(c + 1) * 512 + t * 8];
      else if (t < 192) tmp = *(const uint4*)&vcg[(size_t)(c + 1) * 1024 + (t - 64) * 8];
    }

    bf16x8 kf = *(const bf16x8*)&ldsK[cb][ln * 16 + hf * 8];
    f32x16 S = __builtin_amdgcn_mfma_f32_32x32x16_bf16(kf, qf, zero, 0, 0, 0);

    BF8U f0, f1;
#pragma unroll
    for (int i = 0; i < 4; ++i) {
      f0.u[i] = packbf2(__builtin_amdgcn_exp2f(S[2 * i]),
                        __builtin_amdgcn_exp2f(S[2 * i + 1]));
      f1.u[i] = packbf2(__builtin_amdgcn_exp2f(S[8 + 2 * i]),
                        __builtin_amdgcn_exp2f(S[9 + 2 * i]));
    }

    bf16x8 va = *(const bf16x8*)&ldsV[cb][ln * 16 + hf * 8];
    bf16x8 vb = *(const bf16x8*)&ldsV[cb][512 + ln * 16 + hf * 8];
    acc0 = __builtin_amdgcn_mfma_f32_32x32x16_bf16(va, f0.v, acc0, 0, 0, 0);
    acc1 = __builtin_amdgcn_mfma_f32_32x32x16_bf16(vb, f1.v, acc1, 0, 0, 0);

    if (c + 1 < CPS) {               // write next chunk into the other buffer
      if (t < 64)       *(uint4*)&ldsK[cb ^ 1][t * 8] = tmp;
      else if (t < 192) *(uint4*)&ldsV[cb ^ 1][(t - 64) * 8] = tmp;
    }
    __syncthreads();
  }

  f32x16 acc;
#pragma unroll
  for (int i = 0; i < 16; ++i) acc[i] = acc0[i] + acc1[i];

  // acc: col q = ln, row d = (r&3)+8*(r>>2)+4*hf. Row16 (denom) = acc[8]@hf0.
  unsigned short* prow =
      &Pb[(size_t)(sp * 2 + b) * (NQ * DIM) + (size_t)(q0 + ln) * DIM + h * 16 + 4 * hf];
  uint2 w0, w1;
  w0.x = packbf2(acc[0], acc[1]); w0.y = packbf2(acc[2], acc[3]);
  w1.x = packbf2(acc[4], acc[5]); w1.y = packbf2(acc[6], acc[7]);
  *(uint2*)&prow[0] = w0;
  *(uint2*)&prow[8] = w1;
  if (!hf)
    Lsum[(size_t)(sp * 2 + b) * (HEADS * NQ) + (size_t)h * NQ + q0 + ln] = acc[8];
}

// ---------------------------------------------------------------------------
// proj_comb: fused combine (NSPLIT=2 halves) + reference scramble + proj GEMM.
// u32 combine loads (2 tokens/lane). Proj weights from bf16 Wb.
// grid (200,2), blk 256.
// ---------------------------------------------------------------------------
__global__ __launch_bounds__(256) void proj_comb(
    const unsigned short* __restrict__ Pb, const float* __restrict__ Lsum,
    const bf16_t* __restrict__ Wb, const float* __restrict__ p_b,
    float* __restrict__ Out)
{
  __shared__ __align__(16) unsigned short As[32][136];
  int t = threadIdx.x;
  int b = blockIdx.y;
  int s0 = blockIdx.x * 32;

  {
    int tp = t & 15, cg = t >> 4;          // token pair, 16 channel groups
#pragma unroll
    for (int it = 0; it < 8; ++it) {
      int c = cg * 8 + it;
      int f = c * NQ + s0 + 2 * tp;        // flat att index; even -> d<=14
      int n = f >> 7, hh = (f >> 4) & 7;
      float plo = 0.f, phi = 0.f, L = 0.f;
#pragma unroll
      for (int s = 0; s < NSPLIT; ++s) {
        unsigned u = *(const unsigned*)&Pb[(size_t)(2 * s + b) * (NQ * DIM) + f];
        plo += __uint_as_float(u << 16);
        phi += __uint_as_float(u & 0xFFFF0000u);
        L += Lsum[(size_t)(2 * s + b) * (HEADS * NQ) + (size_t)hh * NQ + n];
      }
      As[2 * tp][c]     = f2bf(plo / L);
      As[2 * tp + 1][c] = f2bf(phi / L);
    }
  }
  __syncthreads();

  int ln = t & 31, hf = (t >> 5) & 1, wid = t >> 6;
  int o = wid * 32 + ln;
  const bf16_t* brow = &Wb[49152 + (size_t)o * DIM + hf * 8];
  const unsigned short* arow = &As[ln][hf * 8];
  f32x16 acc = {};
#pragma unroll
  for (int c0 = 0; c0 < 128; c0 += 16) {
    bf16x8 af = *(const bf16x8*)&arow[c0];
    bf16x8 bf = *(const bf16x8*)&brow[c0];
    acc = __builtin_amdgcn_mfma_f32_32x32x16_bf16(af, bf, acc, 0, 0, 0);
  }
  float bv = p_b[o];
  float* obase = &Out[((size_t)b * DIM + o) * NQ + s0 + 4 * hf];
#pragma unroll
  for (int g = 0; g < 4; ++g) {
    float4 r;
    r.x = acc[4 * g + 0] + bv; r.y = acc[4 * g + 1] + bv;
    r.z = acc[4 * g + 2] + bv; r.w = acc[4 * g + 3] + bv;
    *(float4*)&obase[8 * g] = r;
  }
}

// ---------------------------------------------------------------------------
extern "C" void kernel_launch(void* const* d_in, const int* in_sizes, int n_in,
                              void* d_out, int out_size, void* d_ws, size_t ws_size,
                              hipStream_t stream)
{
  const float* x    = (const float*)d_in[0];
  const float* q_w  = (const float*)d_in[1];
  const float* q_b  = (const float*)d_in[2];
  const float* k_w  = (const float*)d_in[3];
  const float* k_b  = (const float*)d_in[4];
  const float* v_w  = (const float*)d_in[5];
  const float* v_b  = (const float*)d_in[6];
  const float* sr_w = (const float*)d_in[7];
  const float* sr_b = (const float*)d_in[8];
  const float* bng  = (const float*)d_in[9];
  const float* bnb  = (const float*)d_in[10];
  const float* bnm  = (const float*)d_in[11];
  const float* bnv  = (const float*)d_in[12];
  const float* p_w  = (const float*)d_in[13];
  const float* p_b  = (const float*)d_in[14];
  float* out = (float*)d_out;

  float* ws = (float*)d_ws;
  // f32-slot layout, no aliasing:
  bf16_t* Qb   = (bf16_t*)(ws);             // [0, 819200)
  bf16_t* Kp   = (bf16_t*)(ws + 819200);    // [819200, 1024000)
  bf16_t* Vp   = (bf16_t*)(ws + 1024000);   // [1024000, 1433600)
  float*  Lsum = ws + 1433600;              // [1433600, 1945600) up to 10 slices
  bf16_t* Pb   = (bf16_t*)(ws + 1945600);   // [1945600, 6041600) up to 10 slices
  bf16_t* Wb   = (bf16_t*)(ws + 6041600);   // [6041600, 6107136)

  const float sl = 0.25f * LOG2E;  // SCALE * log2(e) folded into Q

  // 1. one-time weight cast (tiny)
  wcast<<<dim3(128), dim3(256), 0, stream>>>(
      q_w, k_w, v_w, p_w, sr_w, (unsigned short*)Wb);

  // 2. fused q + sr->k->v from f32 x (LDS-staged A) + bf16 Wb rows
  mgemm_qsrkv<<<dim3(250, NBATCH), dim3(256), 0, stream>>>(
      x, Wb, q_b, sr_b, k_b, v_b, bng, bnb, bnm, bnv,
      (unsigned short*)Qb, (unsigned short*)Kp, (unsigned short*)Vp, sl);

  // 3. attention partials (kv-split = 2, LDS-staged K/V, block-shared)
  attn_split<<<dim3(NQ / 128, HEADS, 2 * NSPLIT), dim3(256), 0, stream>>>(
      Qb, Kp, Vp, (unsigned short*)Pb, Lsum);

  // 4. combine + scramble + proj -> f32 chan-major final output (B,128,80,80)
  proj_comb<<<dim3(200, NBATCH), dim3(256), 0, stream>>>(
      (const unsigned short*)Pb, Lsum, Wb, p_b, out);
}

// Round 7
// 145.209 us; speedup vs baseline: 1.0802x; 1.0802x over previous
//
#include <hip/hip_runtime.h>
#include <hip/hip_bf16.h>
#include <cmath>

#define DIM 128
#define HEADS 8
#define NBATCH 2
#define NQ 6400   /* 80*80 */
#define NKV 1600  /* 40*40 */
#define NC 50     /* kv chunks of 32 */
#define NSPLIT 2  /* kv-split count */
#define CPS 25    /* chunks per split */
#define BN_EPS 1e-5f
#define LOG2E 1.4426950408889634f

typedef __bf16 bf16_t;
typedef __attribute__((ext_vector_type(8))) __bf16 bf16x8;
typedef __attribute__((ext_vector_type(16))) float f32x16;

union BF8U { bf16x8 v; unsigned u[4]; };

// pack two f32 -> packed bf16 (a->lo, b->hi); lowers to v_cvt_pk_bf16_f32 (RNE)
__device__ inline unsigned packbf2(float a, float b) {
  union { __hip_bfloat162 v; unsigned u; } r;
  r.v = __float22bfloat162_rn(make_float2(a, b));
  return r.u;
}

__device__ inline unsigned short f2bf(float v) {
  unsigned u = __float_as_uint(v);
  return (unsigned short)((u + 0x7FFFu + ((u >> 16) & 1u)) >> 16);
}

// ---------------------------------------------------------------------------
// wcast: one-time f32 -> bf16 weight cast (q|k|v|proj|sr -> Wb). 128 blocks.
// ---------------------------------------------------------------------------
__global__ __launch_bounds__(256) void wcast(
    const float* __restrict__ qw, const float* __restrict__ kw,
    const float* __restrict__ vw, const float* __restrict__ pw,
    const float* __restrict__ srw, unsigned short* __restrict__ Wb)
{
  int e4 = (blockIdx.x * 256 + threadIdx.x) * 4;   // 0..131068, step 4
  const float* src; int idx;
  if (e4 < 16384)      { src = qw;  idx = e4; }
  else if (e4 < 32768) { src = kw;  idx = e4 - 16384; }
  else if (e4 < 49152) { src = vw;  idx = e4 - 32768; }
  else if (e4 < 65536) { src = pw;  idx = e4 - 49152; }
  else                 { src = srw; idx = e4 - 65536; }
  float4 v = *(const float4*)(src + idx);
  uint2 wv;
  wv.x = packbf2(v.x, v.y);
  wv.y = packbf2(v.z, v.w);
  *(uint2*)&Wb[e4] = wv;
}

// ---------------------------------------------------------------------------
// Fused q + (sr -> bn -> relu -> k -> v) GEMMs. A-operands staged from f32 x
// into LDS per block (transpose/im2col fused); B-operands bf16 rows of Wb.
// blocks [0,50): sr->k->v. blocks [50,250): q tile. (unchanged)
// ---------------------------------------------------------------------------
__global__ __launch_bounds__(256) void mgemm_qsrkv(
    const float* __restrict__ x, const bf16_t* __restrict__ Wb,
    const float* __restrict__ q_b, const float* __restrict__ sr_b,
    const float* __restrict__ k_b, const float* __restrict__ v_b,
    const float* __restrict__ bng, const float* __restrict__ bnb,
    const float* __restrict__ bnm, const float* __restrict__ bnv,
    unsigned short* __restrict__ Qb,
    unsigned short* __restrict__ Kp, unsigned short* __restrict__ Vp,
    float sl)
{
  __shared__ __align__(16) unsigned short xs4[32][520]; // sr A tile (im2col)
  __shared__ __align__(16) unsigned short xs[32][136];  // relu out / q A tile
  int t = threadIdx.x;
  int ln = t & 31, hf = (t >> 5) & 1, wid = t >> 6;
  int b = blockIdx.y;
  int o = wid * 32 + ln;

  if (blockIdx.x < 50) {             // ---- sr -> k -> v part ----
    int cid = blockIdx.x;
    int s0 = cid * 32;

    // Stage X4 tile: token tx, values (c,ky,kx) in im2col order c*4+ky*2+kx.
    {
      int tx = t & 31, g = t >> 5;
      int s = s0 + tx;
      int i = s / 40, j = s % 40;
      const float* xb = x + (size_t)b * DIM * NQ;
#pragma unroll
      for (int u = 0; u < 32; ++u) {
        int idx2 = g * 32 + u;       // c*2 + ky
        int c = idx2 >> 1, ky = idx2 & 1;
        const float* src = xb + (size_t)c * NQ + (2 * i + ky) * 80 + 2 * j;
        float2 vv = *(const float2*)src;             // kx = 0,1 contiguous
        *(unsigned*)&xs4[tx][c * 4 + ky * 2] = packbf2(vv.x, vv.y);
      }
    }
    __syncthreads();

    // sr GEMM: K = 512 off the LDS tile; B rows from Wb (bf16).
    const unsigned short* arow = &xs4[ln][hf * 8];
    const bf16_t* brow = &Wb[65536 + (size_t)o * 512 + hf * 8];
    f32x16 acc = {};
#pragma unroll 8
    for (int c0 = 0; c0 < 512; c0 += 16) {
      bf16x8 af = *(const bf16x8*)&arow[c0];
      bf16x8 bf = *(const bf16x8*)&brow[c0];
      acc = __builtin_amdgcn_mfma_f32_32x32x16_bf16(af, bf, acc, 0, 0, 0);
    }
    float bv = sr_b[o];
    float inv = bng[o] / sqrtf(bnv[o] + BN_EPS);
    float b2 = bnb[o] - bnm[o] * inv;
#pragma unroll
    for (int g = 0; g < 4; ++g)
#pragma unroll
      for (int jj = 0; jj < 4; ++jj) {
        int sr = 8 * g + 4 * hf + jj;
        xs[sr][o] = f2bf(fmaxf((acc[4 * g + jj] + bv) * inv + b2, 0.f));
      }
    __syncthreads();

    // k + v GEMMs (C=128) off the LDS tile, bf16 weight rows
    const unsigned short* ar2 = &xs[ln][hf * 8];
    const bf16_t* kbrow = &Wb[16384 + (size_t)o * DIM + hf * 8];
    const bf16_t* vbrow = &Wb[32768 + (size_t)o * DIM + hf * 8];
    f32x16 ka = {}, va = {};
#pragma unroll
    for (int c0 = 0; c0 < 128; c0 += 16) {
      bf16x8 af = *(const bf16x8*)&ar2[c0];
      bf16x8 kb = *(const bf16x8*)&kbrow[c0];
      bf16x8 vb = *(const bf16x8*)&vbrow[c0];
      ka = __builtin_amdgcn_mfma_f32_32x32x16_bf16(af, kb, ka, 0, 0, 0);
      va = __builtin_amdgcn_mfma_f32_32x32x16_bf16(af, vb, va, 0, 0, 0);
    }
    int hloc = o >> 4, d = o & 15;
    {
      float kb2 = k_b[o];
      size_t CB = (((size_t)b * HEADS + hloc) * NC + cid) * 512;
#pragma unroll
      for (int g = 0; g < 4; ++g)
#pragma unroll
        for (int jj = 0; jj < 4; ++jj) {
          int sl2 = 8 * g + 4 * hf + jj;
          Kp[CB + sl2 * 16 + d] = f2bf(ka[4 * g + jj] + kb2);
        }
    }
    {
      float vb2 = v_b[o];
      size_t CB = (((size_t)b * HEADS + hloc) * NC + cid) * 1024;
      uint4 w0, w1;
      w0.x = packbf2(va[0] + vb2, va[1] + vb2);
      w0.y = packbf2(va[2] + vb2, va[3] + vb2);
      w0.z = packbf2(va[4] + vb2, va[5] + vb2);
      w0.w = packbf2(va[6] + vb2, va[7] + vb2);
      w1.x = packbf2(va[8] + vb2, va[9] + vb2);
      w1.y = packbf2(va[10] + vb2, va[11] + vb2);
      w1.z = packbf2(va[12] + vb2, va[13] + vb2);
      w1.w = packbf2(va[14] + vb2, va[15] + vb2);
      *(uint4*)&Vp[CB + d * 16 + hf * 8] = w0;       // va block
      *(uint4*)&Vp[CB + 512 + d * 16 + hf * 8] = w1; // vb block
    }
    // Vp lane-16 (denominator) rows for this (b, chunk), all 8 heads
    {
      int hh = t >> 5, pos = t & 31;
      size_t addr = (((size_t)b * HEADS + hh) * NC + cid) * 1024 + 256 +
                    ((pos & 16) ? 512 : 0) + (pos & 15);
      Vp[addr] = 0x3F80;               // 1.0 bf16
    }
  } else {                           // ---- q part (C = 128) ----
    int s0 = (blockIdx.x - 50) * 32;

    // Stage 32-token x 128-channel bf16 tile, token-major (coalesced reads).
    {
      int tx = t & 31, cg = t >> 5;
      const float* xb = x + (size_t)b * DIM * NQ + s0 + tx;
#pragma unroll
      for (int it = 0; it < 8; ++it) {
        int c = 2 * cg + 16 * it;
        float a0 = xb[(size_t)c * NQ];
        float a1 = xb[(size_t)(c + 1) * NQ];
        *(unsigned*)&xs[tx][c] = packbf2(a0, a1);
      }
    }
    __syncthreads();

    const unsigned short* arow = &xs[ln][hf * 8];
    const bf16_t* brow = &Wb[(size_t)o * DIM + hf * 8];
    f32x16 acc = {};
#pragma unroll
    for (int c0 = 0; c0 < 128; c0 += 16) {
      bf16x8 af = *(const bf16x8*)&arow[c0];
      bf16x8 bf = *(const bf16x8*)&brow[c0];
      acc = __builtin_amdgcn_mfma_f32_32x32x16_bf16(af, bf, acc, 0, 0, 0);
    }
    float bv = q_b[o];
#pragma unroll
    for (int g = 0; g < 4; ++g)
#pragma unroll
      for (int jj = 0; jj < 4; ++jj) {
        int sq = s0 + 8 * g + 4 * hf + jj;
        Qb[((size_t)b * NQ + sq) * DIM + o] = f2bf((acc[4 * g + jj] + bv) * sl);
      }
  }
}

// ---------------------------------------------------------------------------
// MFMA attention, low-register body (round-6, resubmitted after infra fail).
// Diagnosis: rocprof VGPR_Count excludes AGPRs — R2's body held ~145 total
// regs (acc0,acc1,S0,S1 + 9 prefetch frags) -> 3 waves/SIMD cap -> 1500cy/
// iter of exposed L2 latency. Fixes: (1) single accumulator via chained
// mfma; (2) S computed in-iter; (3) two named prefetch slots A/B processed
// per iteration, each refilled right after its fragments die (~1 iter
// load->use distance, no runtime-indexed arrays). State ~85 regs -> 6
// waves/SIMD cap; TLP hides latency. No LDS, no barriers.
// grid (50, 8, 4): z = b + 2*split. block 256.
// ---------------------------------------------------------------------------
__global__ __launch_bounds__(256) void attn_split(
    const bf16_t* __restrict__ Qb, const bf16_t* __restrict__ Kp,
    const bf16_t* __restrict__ Vp, unsigned short* __restrict__ Pb,
    float* __restrict__ Lsum)
{
  const int t = threadIdx.x;
  const int ln = t & 31, hf = (t >> 5) & 1, wid = t >> 6;
  const int h = blockIdx.y;
  const int b = blockIdx.z & 1, sp = blockIdx.z >> 1;
  const int q0 = blockIdx.x * 128 + wid * 32;

  bf16x8 qf = *(const bf16x8*)&Qb[((size_t)b * NQ + q0 + ln) * DIM + h * 16 + hf * 8];
  const int bh = b * HEADS + h;
  const bf16_t* kc = &Kp[((size_t)bh * NC + sp * CPS) * 512 + ln * 16 + hf * 8];
  const bf16_t* vc = &Vp[((size_t)bh * NC + sp * CPS) * 1024 + ln * 16 + hf * 8];

  f32x16 acc = {};
  const f32x16 zero = {};

  // slot A <- chunk 0, slot B <- chunk 1
  bf16x8 kA  = *(const bf16x8*)kc;
  bf16x8 vaA = *(const bf16x8*)vc;
  bf16x8 vbA = *(const bf16x8*)(vc + 512);
  bf16x8 kB  = *(const bf16x8*)(kc + 512);
  bf16x8 vaB = *(const bf16x8*)(vc + 1024);
  bf16x8 vbB = *(const bf16x8*)(vc + 1536);

  for (int i = 0; i < 12; ++i) {
    // ---- process slot A = chunk 2i ----
    f32x16 S = __builtin_amdgcn_mfma_f32_32x32x16_bf16(kA, qf, zero, 0, 0, 0);
    kA = *(const bf16x8*)(kc + (size_t)(2 * i + 2) * 512);     // refill kA
    BF8U f0, f1;
#pragma unroll
    for (int j = 0; j < 4; ++j) {
      f0.u[j] = packbf2(__builtin_amdgcn_exp2f(S[2 * j]),
                        __builtin_amdgcn_exp2f(S[2 * j + 1]));
      f1.u[j] = packbf2(__builtin_amdgcn_exp2f(S[8 + 2 * j]),
                        __builtin_amdgcn_exp2f(S[9 + 2 * j]));
    }
    acc = __builtin_amdgcn_mfma_f32_32x32x16_bf16(vaA, f0.v, acc, 0, 0, 0);
    acc = __builtin_amdgcn_mfma_f32_32x32x16_bf16(vbA, f1.v, acc, 0, 0, 0);
    vaA = *(const bf16x8*)(vc + (size_t)(2 * i + 2) * 1024);   // refill vA
    vbA = *(const bf16x8*)(vc + (size_t)(2 * i + 2) * 1024 + 512);

    // ---- process slot B = chunk 2i+1 ----
    int c3 = (2 * i + 3 < CPS) ? 2 * i + 3 : CPS - 1;          // clamp (OOB-safe)
    f32x16 T = __builtin_amdgcn_mfma_f32_32x32x16_bf16(kB, qf, zero, 0, 0, 0);
    kB = *(const bf16x8*)(kc + (size_t)c3 * 512);              // refill kB
    BF8U g0, g1;
#pragma unroll
    for (int j = 0; j < 4; ++j) {
      g0.u[j] = packbf2(__builtin_amdgcn_exp2f(T[2 * j]),
                        __builtin_amdgcn_exp2f(T[2 * j + 1]));
      g1.u[j] = packbf2(__builtin_amdgcn_exp2f(T[8 + 2 * j]),
                        __builtin_amdgcn_exp2f(T[9 + 2 * j]));
    }
    acc = __builtin_amdgcn_mfma_f32_32x32x16_bf16(vaB, g0.v, acc, 0, 0, 0);
    acc = __builtin_amdgcn_mfma_f32_32x32x16_bf16(vbB, g1.v, acc, 0, 0, 0);
    vaB = *(const bf16x8*)(vc + (size_t)c3 * 1024);            // refill vB
    vbB = *(const bf16x8*)(vc + (size_t)c3 * 1024 + 512);
  }
  {
    // ---- tail: chunk 24 (in slot A) ----
    f32x16 S = __builtin_amdgcn_mfma_f32_32x32x16_bf16(kA, qf, zero, 0, 0, 0);
    BF8U f0, f1;
#pragma unroll
    for (int j = 0; j < 4; ++j) {
      f0.u[j] = packbf2(__builtin_amdgcn_exp2f(S[2 * j]),
                        __builtin_amdgcn_exp2f(S[2 * j + 1]));
      f1.u[j] = packbf2(__builtin_amdgcn_exp2f(S[8 + 2 * j]),
                        __builtin_amdgcn_exp2f(S[9 + 2 * j]));
    }
    acc = __builtin_amdgcn_mfma_f32_32x32x16_bf16(vaA, f0.v, acc, 0, 0, 0);
    acc = __builtin_amdgcn_mfma_f32_32x32x16_bf16(vbA, f1.v, acc, 0, 0, 0);
  }

  // acc: col q = ln, row d = (r&3)+8*(r>>2)+4*hf. Row16 (denom) = acc[8]@hf0.
  unsigned short* prow =
      &Pb[(size_t)(sp * 2 + b) * (NQ * DIM) + (size_t)(q0 + ln) * DIM + h * 16 + 4 * hf];
  uint2 w0, w1;
  w0.x = packbf2(acc[0], acc[1]); w0.y = packbf2(acc[2], acc[3]);
  w1.x = packbf2(acc[4], acc[5]); w1.y = packbf2(acc[6], acc[7]);
  *(uint2*)&prow[0] = w0;
  *(uint2*)&prow[8] = w1;
  if (!hf)
    Lsum[(size_t)(sp * 2 + b) * (HEADS * NQ) + (size_t)h * NQ + q0 + ln] = acc[8];
}

// ---------------------------------------------------------------------------
// proj_comb: fused combine (NSPLIT=2 halves) + reference scramble + proj GEMM.
// u32 combine loads (2 tokens/lane). Proj weights from bf16 Wb.
// grid (200,2), blk 256.
// ---------------------------------------------------------------------------
__global__ __launch_bounds__(256) void proj_comb(
    const unsigned short* __restrict__ Pb, const float* __restrict__ Lsum,
    const bf16_t* __restrict__ Wb, const float* __restrict__ p_b,
    float* __restrict__ Out)
{
  __shared__ __align__(16) unsigned short As[32][136];
  int t = threadIdx.x;
  int b = blockIdx.y;
  int s0 = blockIdx.x * 32;

  {
    int tp = t & 15, cg = t >> 4;          // token pair, 16 channel groups
#pragma unroll
    for (int it = 0; it < 8; ++it) {
      int c = cg * 8 + it;
      int f = c * NQ + s0 + 2 * tp;        // flat att index; even -> d<=14
      int n = f >> 7, hh = (f >> 4) & 7;
      float plo = 0.f, phi = 0.f, L = 0.f;
#pragma unroll
      for (int s = 0; s < NSPLIT; ++s) {
        unsigned u = *(const unsigned*)&Pb[(size_t)(2 * s + b) * (NQ * DIM) + f];
        plo += __uint_as_float(u << 16);
        phi += __uint_as_float(u & 0xFFFF0000u);
        L += Lsum[(size_t)(2 * s + b) * (HEADS * NQ) + (size_t)hh * NQ + n];
      }
      As[2 * tp][c]     = f2bf(plo / L);
      As[2 * tp + 1][c] = f2bf(phi / L);
    }
  }
  __syncthreads();

  int ln = t & 31, hf = (t >> 5) & 1, wid = t >> 6;
  int o = wid * 32 + ln;
  const bf16_t* brow = &Wb[49152 + (size_t)o * DIM + hf * 8];
  const unsigned short* arow = &As[ln][hf * 8];
  f32x16 acc = {};
#pragma unroll
  for (int c0 = 0; c0 < 128; c0 += 16) {
    bf16x8 af = *(const bf16x8*)&arow[c0];
    bf16x8 bf = *(const bf16x8*)&brow[c0];
    acc = __builtin_amdgcn_mfma_f32_32x32x16_bf16(af, bf, acc, 0, 0, 0);
  }
  float bv = p_b[o];
  float* obase = &Out[((size_t)b * DIM + o) * NQ + s0 + 4 * hf];
#pragma unroll
  for (int g = 0; g < 4; ++g) {
    float4 r;
    r.x = acc[4 * g + 0] + bv; r.y = acc[4 * g + 1] + bv;
    r.z = acc[4 * g + 2] + bv; r.w = acc[4 * g + 3] + bv;
    *(float4*)&obase[8 * g] = r;
  }
}

// ---------------------------------------------------------------------------
extern "C" void kernel_launch(void* const* d_in, const int* in_sizes, int n_in,
                              void* d_out, int out_size, void* d_ws, size_t ws_size,
                              hipStream_t stream)
{
  const float* x    = (const float*)d_in[0];
  const float* q_w  = (const float*)d_in[1];
  const float* q_b  = (const float*)d_in[2];
  const float* k_w  = (const float*)d_in[3];
  const float* k_b  = (const float*)d_in[4];
  const float* v_w  = (const float*)d_in[5];
  const float* v_b  = (const float*)d_in[6];
  const float* sr_w = (const float*)d_in[7];
  const float* sr_b = (const float*)d_in[8];
  const float* bng  = (const float*)d_in[9];
  const float* bnb  = (const float*)d_in[10];
  const float* bnm  = (const float*)d_in[11];
  const float* bnv  = (const float*)d_in[12];
  const float* p_w  = (const float*)d_in[13];
  const float* p_b  = (const float*)d_in[14];
  float* out = (float*)d_out;

  float* ws = (float*)d_ws;
  // f32-slot layout, no aliasing:
  bf16_t* Qb   = (bf16_t*)(ws);             // [0, 819200)
  bf16_t* Kp   = (bf16_t*)(ws + 819200);    // [819200, 1024000)
  bf16_t* Vp   = (bf16_t*)(ws + 1024000);   // [1024000, 1433600)
  float*  Lsum = ws + 1433600;              // [1433600, 1945600)
  bf16_t* Pb   = (bf16_t*)(ws + 1945600);   // [1945600, 6041600)
  bf16_t* Wb   = (bf16_t*)(ws + 6041600);   // [6041600, 6107136)

  const float sl = 0.25f * LOG2E;  // SCALE * log2(e) folded into Q

  // 1. one-time weight cast (tiny)
  wcast<<<dim3(128), dim3(256), 0, stream>>>(
      q_w, k_w, v_w, p_w, sr_w, (unsigned short*)Wb);

  // 2. fused q + sr->k->v from f32 x (LDS-staged A) + bf16 Wb rows
  mgemm_qsrkv<<<dim3(250, NBATCH), dim3(256), 0, stream>>>(
      x, Wb, q_b, sr_b, k_b, v_b, bng, bnb, bnm, bnv,
      (unsigned short*)Qb, (unsigned short*)Kp, (unsigned short*)Vp, sl);

  // 3. attention partials (kv-split = 2, low-register 2-slot body)
  attn_split<<<dim3(NQ / 128, HEADS, 2 * NSPLIT), dim3(256), 0, stream>>>(
      Qb, Kp, Vp, (unsigned short*)Pb, Lsum);

  // 4. combine + scramble + proj -> f32 chan-major final output (B,128,80,80)
  proj_comb<<<dim3(200, NBATCH), dim3(256), 0, stream>>>(
      (const unsigned short*)Pb, Lsum, Wb, p_b, out);
}

// Round 9
// 137.760 us; speedup vs baseline: 1.1386x; 1.0541x over previous
//
#include <hip/hip_runtime.h>
#include <hip/hip_bf16.h>
#include <cmath>

#define DIM 128
#define HEADS 8
#define NBATCH 2
#define NQ 6400   /* 80*80 */
#define NKV 1600  /* 40*40 */
#define NC 50     /* kv chunks of 32 */
#define BN_EPS 1e-5f
#define LOG2E 1.4426950408889634f

typedef __bf16 bf16_t;
typedef __attribute__((ext_vector_type(8))) __bf16 bf16x8;
typedef __attribute__((ext_vector_type(16))) float f32x16;

union BF8U { bf16x8 v; unsigned u[4]; };

// pack two f32 -> packed bf16 (a->lo, b->hi); lowers to v_cvt_pk_bf16_f32 (RNE)
__device__ inline unsigned packbf2(float a, float b) {
  union { __hip_bfloat162 v; unsigned u; } r;
  r.v = __float22bfloat162_rn(make_float2(a, b));
  return r.u;
}

__device__ inline unsigned short f2bf(float v) {
  unsigned u = __float_as_uint(v);
  return (unsigned short)((u + 0x7FFFu + ((u >> 16) & 1u)) >> 16);
}

// ---------------------------------------------------------------------------
// wcast: one-time f32 -> bf16 weight cast (q|k|v|proj|sr -> Wb). 128 blocks.
// ---------------------------------------------------------------------------
__global__ __launch_bounds__(256) void wcast(
    const float* __restrict__ qw, const float* __restrict__ kw,
    const float* __restrict__ vw, const float* __restrict__ pw,
    const float* __restrict__ srw, unsigned short* __restrict__ Wb)
{
  int e4 = (blockIdx.x * 256 + threadIdx.x) * 4;   // 0..131068, step 4
  const float* src; int idx;
  if (e4 < 16384)      { src = qw;  idx = e4; }
  else if (e4 < 32768) { src = kw;  idx = e4 - 16384; }
  else if (e4 < 49152) { src = vw;  idx = e4 - 32768; }
  else if (e4 < 65536) { src = pw;  idx = e4 - 49152; }
  else                 { src = srw; idx = e4 - 65536; }
  float4 v = *(const float4*)(src + idx);
  uint2 wv;
  wv.x = packbf2(v.x, v.y);
  wv.y = packbf2(v.z, v.w);
  *(uint2*)&Wb[e4] = wv;
}

// ---------------------------------------------------------------------------
// Fused q + (sr -> bn -> relu -> k -> v) GEMMs. A-operands staged from f32 x
// into LDS per block (transpose/im2col fused); B-operands bf16 rows of Wb.
// blocks [0,50): sr->k->v. blocks [50,250): q tile. (unchanged)
// ---------------------------------------------------------------------------
__global__ __launch_bounds__(256) void mgemm_qsrkv(
    const float* __restrict__ x, const bf16_t* __restrict__ Wb,
    const float* __restrict__ q_b, const float* __restrict__ sr_b,
    const float* __restrict__ k_b, const float* __restrict__ v_b,
    const float* __restrict__ bng, const float* __restrict__ bnb,
    const float* __restrict__ bnm, const float* __restrict__ bnv,
    unsigned short* __restrict__ Qb,
    unsigned short* __restrict__ Kp, unsigned short* __restrict__ Vp,
    float sl)
{
  __shared__ __align__(16) unsigned short xs4[32][520]; // sr A tile (im2col)
  __shared__ __align__(16) unsigned short xs[32][136];  // relu out / q A tile
  int t = threadIdx.x;
  int ln = t & 31, hf = (t >> 5) & 1, wid = t >> 6;
  int b = blockIdx.y;
  int o = wid * 32 + ln;

  if (blockIdx.x < 50) {             // ---- sr -> k -> v part ----
    int cid = blockIdx.x;
    int s0 = cid * 32;

    // Stage X4 tile: token tx, values (c,ky,kx) in im2col order c*4+ky*2+kx.
    {
      int tx = t & 31, g = t >> 5;
      int s = s0 + tx;
      int i = s / 40, j = s % 40;
      const float* xb = x + (size_t)b * DIM * NQ;
#pragma unroll
      for (int u = 0; u < 32; ++u) {
        int idx2 = g * 32 + u;       // c*2 + ky
        int c = idx2 >> 1, ky = idx2 & 1;
        const float* src = xb + (size_t)c * NQ + (2 * i + ky) * 80 + 2 * j;
        float2 vv = *(const float2*)src;             // kx = 0,1 contiguous
        *(unsigned*)&xs4[tx][c * 4 + ky * 2] = packbf2(vv.x, vv.y);
      }
    }
    __syncthreads();

    // sr GEMM: K = 512 off the LDS tile; B rows from Wb (bf16).
    const unsigned short* arow = &xs4[ln][hf * 8];
    const bf16_t* brow = &Wb[65536 + (size_t)o * 512 + hf * 8];
    f32x16 acc = {};
#pragma unroll 8
    for (int c0 = 0; c0 < 512; c0 += 16) {
      bf16x8 af = *(const bf16x8*)&arow[c0];
      bf16x8 bf = *(const bf16x8*)&brow[c0];
      acc = __builtin_amdgcn_mfma_f32_32x32x16_bf16(af, bf, acc, 0, 0, 0);
    }
    float bv = sr_b[o];
    float inv = bng[o] / sqrtf(bnv[o] + BN_EPS);
    float b2 = bnb[o] - bnm[o] * inv;
#pragma unroll
    for (int g = 0; g < 4; ++g)
#pragma unroll
      for (int jj = 0; jj < 4; ++jj) {
        int sr = 8 * g + 4 * hf + jj;
        xs[sr][o] = f2bf(fmaxf((acc[4 * g + jj] + bv) * inv + b2, 0.f));
      }
    __syncthreads();

    // k + v GEMMs (C=128) off the LDS tile, bf16 weight rows
    const unsigned short* ar2 = &xs[ln][hf * 8];
    const bf16_t* kbrow = &Wb[16384 + (size_t)o * DIM + hf * 8];
    const bf16_t* vbrow = &Wb[32768 + (size_t)o * DIM + hf * 8];
    f32x16 ka = {}, va = {};
#pragma unroll
    for (int c0 = 0; c0 < 128; c0 += 16) {
      bf16x8 af = *(const bf16x8*)&ar2[c0];
      bf16x8 kb = *(const bf16x8*)&kbrow[c0];
      bf16x8 vb = *(const bf16x8*)&vbrow[c0];
      ka = __builtin_amdgcn_mfma_f32_32x32x16_bf16(af, kb, ka, 0, 0, 0);
      va = __builtin_amdgcn_mfma_f32_32x32x16_bf16(af, vb, va, 0, 0, 0);
    }
    int hloc = o >> 4, d = o & 15;
    {
      float kb2 = k_b[o];
      size_t CB = (((size_t)b * HEADS + hloc) * NC + cid) * 512;
#pragma unroll
      for (int g = 0; g < 4; ++g)
#pragma unroll
        for (int jj = 0; jj < 4; ++jj) {
          int sl2 = 8 * g + 4 * hf + jj;
          Kp[CB + sl2 * 16 + d] = f2bf(ka[4 * g + jj] + kb2);
        }
    }
    {
      float vb2 = v_b[o];
      size_t CB = (((size_t)b * HEADS + hloc) * NC + cid) * 1024;
      uint4 w0, w1;
      w0.x = packbf2(va[0] + vb2, va[1] + vb2);
      w0.y = packbf2(va[2] + vb2, va[3] + vb2);
      w0.z = packbf2(va[4] + vb2, va[5] + vb2);
      w0.w = packbf2(va[6] + vb2, va[7] + vb2);
      w1.x = packbf2(va[8] + vb2, va[9] + vb2);
      w1.y = packbf2(va[10] + vb2, va[11] + vb2);
      w1.z = packbf2(va[12] + vb2, va[13] + vb2);
      w1.w = packbf2(va[14] + vb2, va[15] + vb2);
      *(uint4*)&Vp[CB + d * 16 + hf * 8] = w0;       // va block
      *(uint4*)&Vp[CB + 512 + d * 16 + hf * 8] = w1; // vb block
    }
    // Vp lane-16 (denominator) rows for this (b, chunk), all 8 heads
    {
      int hh = t >> 5, pos = t & 31;
      size_t addr = (((size_t)b * HEADS + hh) * NC + cid) * 1024 + 256 +
                    ((pos & 16) ? 512 : 0) + (pos & 15);
      Vp[addr] = 0x3F80;               // 1.0 bf16
    }
  } else {                           // ---- q part (C = 128) ----
    int s0 = (blockIdx.x - 50) * 32;

    // Stage 32-token x 128-channel bf16 tile, token-major (coalesced reads).
    {
      int tx = t & 31, cg = t >> 5;
      const float* xb = x + (size_t)b * DIM * NQ + s0 + tx;
#pragma unroll
      for (int it = 0; it < 8; ++it) {
        int c = 2 * cg + 16 * it;
        float a0 = xb[(size_t)c * NQ];
        float a1 = xb[(size_t)(c + 1) * NQ];
        *(unsigned*)&xs[tx][c] = packbf2(a0, a1);
      }
    }
    __syncthreads();

    const unsigned short* arow = &xs[ln][hf * 8];
    const bf16_t* brow = &Wb[(size_t)o * DIM + hf * 8];
    f32x16 acc = {};
#pragma unroll
    for (int c0 = 0; c0 < 128; c0 += 16) {
      bf16x8 af = *(const bf16x8*)&arow[c0];
      bf16x8 bf = *(const bf16x8*)&brow[c0];
      acc = __builtin_amdgcn_mfma_f32_32x32x16_bf16(af, bf, acc, 0, 0, 0);
    }
    float bv = q_b[o];
#pragma unroll
    for (int g = 0; g < 4; ++g)
#pragma unroll
      for (int jj = 0; jj < 4; ++jj) {
        int sq = s0 + 8 * g + 4 * hf + jj;
        Qb[((size_t)b * NQ + sq) * DIM + o] = f2bf((acc[4 * g + jj] + bv) * sl);
      }
  }
}

// ---------------------------------------------------------------------------
// MFMA attention, round-9 (= round-8 body): full softmax per block, no
// kv-split. Block = (b, h, 32-q tile); its 4 waves split the 50-chunk K/V
// stream stride-4. Grid (200,8,2) = 3200 blocks = 12.5/CU; ~50-reg body
// -> up to 8 waves/SIMD residency: TLP hides the ~200cy L2 gather latency
// that kept R2/R3/R7 at 42-44 us. Epilogue: cross-wave LDS reduce
// (R[4][9][64] = 9 KB, conflict-free), wave 0 normalizes by the denominator
// (Vp row-16 trick -> acc[8]@hf0) and writes FINAL bf16 P (token-major).
// Eliminates Lsum + multi-slice Pb + proj combine entirely.
// ---------------------------------------------------------------------------
__global__ __launch_bounds__(256) void attn_full(
    const bf16_t* __restrict__ Qb, const bf16_t* __restrict__ Kp,
    const bf16_t* __restrict__ Vp, unsigned short* __restrict__ Pb)
{
  __shared__ float R[4][9][64];

  const int t = threadIdx.x;
  const int ln = t & 31, hf = (t >> 5) & 1, wid = t >> 6;
  const int h = blockIdx.y;
  const int b = blockIdx.z;
  const int q0 = blockIdx.x * 32;

  bf16x8 qf = *(const bf16x8*)&Qb[((size_t)b * NQ + q0 + ln) * DIM + h * 16 + hf * 8];
  const int bh = b * HEADS + h;
  const bf16_t* kc = &Kp[(size_t)bh * NC * 512 + ln * 16 + hf * 8];
  const bf16_t* vc = &Vp[(size_t)bh * NC * 1024 + ln * 16 + hf * 8];

  f32x16 acc = {};
  const f32x16 zero = {};

  for (int c = wid; c < NC; c += 4) {
    bf16x8 kf = *(const bf16x8*)(kc + (size_t)c * 512);
    bf16x8 va = *(const bf16x8*)(vc + (size_t)c * 1024);
    bf16x8 vb = *(const bf16x8*)(vc + (size_t)c * 1024 + 512);

    f32x16 S = __builtin_amdgcn_mfma_f32_32x32x16_bf16(kf, qf, zero, 0, 0, 0);
    BF8U f0, f1;
#pragma unroll
    for (int j = 0; j < 4; ++j) {
      f0.u[j] = packbf2(__builtin_amdgcn_exp2f(S[2 * j]),
                        __builtin_amdgcn_exp2f(S[2 * j + 1]));
      f1.u[j] = packbf2(__builtin_amdgcn_exp2f(S[8 + 2 * j]),
                        __builtin_amdgcn_exp2f(S[9 + 2 * j]));
    }
    acc = __builtin_amdgcn_mfma_f32_32x32x16_bf16(va, f0.v, acc, 0, 0, 0);
    acc = __builtin_amdgcn_mfma_f32_32x32x16_bf16(vb, f1.v, acc, 0, 0, 0);
  }

  // cross-wave reduction (rows 0..8 only; row 8 = denominator at hf=0)
#pragma unroll
  for (int r = 0; r < 9; ++r) R[wid][r][t & 63] = acc[r];
  __syncthreads();

  if (wid == 0) {                    // wave 0: reduce + normalize + write
    int l64 = t & 63;
    float s[9];
#pragma unroll
    for (int r = 0; r < 9; ++r)
      s[r] = R[0][r][l64] + R[1][r][l64] + R[2][r][l64] + R[3][r][l64];
    float L = hf ? (R[0][8][ln] + R[1][8][ln] + R[2][8][ln] + R[3][8][ln])
                 : s[8];
    float inv = __builtin_amdgcn_rcpf(L);

    // s[0..3] -> d = 4*hf+0..3 ; s[4..7] -> d = 8+4*hf+0..3 (col q = ln)
    unsigned short* prow =
        &Pb[(size_t)b * (NQ * DIM) + (size_t)(q0 + ln) * DIM + h * 16 + 4 * hf];
    uint2 w0, w1;
    w0.x = packbf2(s[0] * inv, s[1] * inv);
    w0.y = packbf2(s[2] * inv, s[3] * inv);
    w1.x = packbf2(s[4] * inv, s[5] * inv);
    w1.y = packbf2(s[6] * inv, s[7] * inv);
    *(uint2*)&prow[0] = w0;
    *(uint2*)&prow[8] = w1;
  }
}

// ---------------------------------------------------------------------------
// proj: reference scramble + proj GEMM (round-9 fix: round 8 dropped the
// scramble — the reshape (B,N,h*d)->(B,C,H,W) is a flat transpose, so
// A[s][c] = Pb[flat = c*NQ + s], NOT Pb[s*128+c]). LDS gather stage is
// proj_comb's proven pattern (u32 loads = 2 tokens/lane), minus the
// Lsum/divide/combine (Pb is already final normalized bf16).
// grid (200,2), blk 256.
// ---------------------------------------------------------------------------
__global__ __launch_bounds__(256) void proj(
    const unsigned short* __restrict__ Pb, const bf16_t* __restrict__ Wb,
    const float* __restrict__ p_b, float* __restrict__ Out)
{
  __shared__ __align__(16) unsigned short As[32][136];
  int t = threadIdx.x;
  int b = blockIdx.y;
  int s0 = blockIdx.x * 32;

  {
    int tp = t & 15, cg = t >> 4;          // token pair, 16 channel groups
    const unsigned short* pbase = Pb + (size_t)b * (NQ * DIM);
#pragma unroll
    for (int it = 0; it < 8; ++it) {
      int c = cg * 8 + it;
      int f = c * NQ + s0 + 2 * tp;        // flat att index (even -> aligned)
      unsigned u = *(const unsigned*)&pbase[f];
      As[2 * tp][c]     = (unsigned short)(u & 0xFFFFu);
      As[2 * tp + 1][c] = (unsigned short)(u >> 16);
    }
  }
  __syncthreads();

  int ln = t & 31, hf = (t >> 5) & 1, wid = t >> 6;
  int o = wid * 32 + ln;
  const bf16_t* brow = &Wb[49152 + (size_t)o * DIM + hf * 8];
  const unsigned short* arow = &As[ln][hf * 8];
  f32x16 acc = {};
#pragma unroll
  for (int c0 = 0; c0 < 128; c0 += 16) {
    bf16x8 af = *(const bf16x8*)&arow[c0];
    bf16x8 bf = *(const bf16x8*)&brow[c0];
    acc = __builtin_amdgcn_mfma_f32_32x32x16_bf16(af, bf, acc, 0, 0, 0);
  }
  float bv = p_b[o];
  float* obase = &Out[((size_t)b * DIM + o) * NQ + s0 + 4 * hf];
#pragma unroll
  for (int g = 0; g < 4; ++g) {
    float4 r;
    r.x = acc[4 * g + 0] + bv; r.y = acc[4 * g + 1] + bv;
    r.z = acc[4 * g + 2] + bv; r.w = acc[4 * g + 3] + bv;
    *(float4*)&obase[8 * g] = r;
  }
}

// ---------------------------------------------------------------------------
extern "C" void kernel_launch(void* const* d_in, const int* in_sizes, int n_in,
                              void* d_out, int out_size, void* d_ws, size_t ws_size,
                              hipStream_t stream)
{
  const float* x    = (const float*)d_in[0];
  const float* q_w  = (const float*)d_in[1];
  const float* q_b  = (const float*)d_in[2];
  const float* k_w  = (const float*)d_in[3];
  const float* k_b  = (const float*)d_in[4];
  const float* v_w  = (const float*)d_in[5];
  const float* v_b  = (const float*)d_in[6];
  const float* sr_w = (const float*)d_in[7];
  const float* sr_b = (const float*)d_in[8];
  const float* bng  = (const float*)d_in[9];
  const float* bnb  = (const float*)d_in[10];
  const float* bnm  = (const float*)d_in[11];
  const float* bnv  = (const float*)d_in[12];
  const float* p_w  = (const float*)d_in[13];
  const float* p_b  = (const float*)d_in[14];
  float* out = (float*)d_out;

  float* ws = (float*)d_ws;
  // f32-slot layout, no aliasing:
  bf16_t* Qb   = (bf16_t*)(ws);             // [0, 819200)
  bf16_t* Kp   = (bf16_t*)(ws + 819200);    // [819200, 1024000)
  bf16_t* Vp   = (bf16_t*)(ws + 1024000);   // [1024000, 1433600)
  bf16_t* Pb   = (bf16_t*)(ws + 1433600);   // [1433600, 2252800) 2 slices
  bf16_t* Wb   = (bf16_t*)(ws + 2252800);   // [2252800, 2318336)

  const float sl = 0.25f * LOG2E;  // SCALE * log2(e) folded into Q

  // 1. one-time weight cast (tiny)
  wcast<<<dim3(128), dim3(256), 0, stream>>>(
      q_w, k_w, v_w, p_w, sr_w, (unsigned short*)Wb);

  // 2. fused q + sr->k->v from f32 x (LDS-staged A) + bf16 Wb rows
  mgemm_qsrkv<<<dim3(250, NBATCH), dim3(256), 0, stream>>>(
      x, Wb, q_b, sr_b, k_b, v_b, bng, bnb, bnm, bnv,
      (unsigned short*)Qb, (unsigned short*)Kp, (unsigned short*)Vp, sl);

  // 3. full attention (no kv-split): in-block reduce + normalize -> final P
  attn_full<<<dim3(NQ / 32, HEADS, NBATCH), dim3(256), 0, stream>>>(
      Qb, Kp, Vp, (unsigned short*)Pb);

  // 4. scramble + proj GEMM -> f32 chan-major final output (B,128,80,80)
  proj<<<dim3(200, NBATCH), dim3(256), 0, stream>>>(
      (const unsigned short*)Pb, Wb, p_b, out);
}

// Round 10
// 136.592 us; speedup vs baseline: 1.1483x; 1.0085x over previous
//
#include <hip/hip_runtime.h>
#include <hip/hip_bf16.h>
#include <cmath>

#define DIM 128
#define HEADS 8
#define NBATCH 2
#define NQ 6400   /* 80*80 */
#define NKV 1600  /* 40*40 */
#define NC 50     /* kv chunks of 32 */
#define BN_EPS 1e-5f
#define LOG2E 1.4426950408889634f

typedef __bf16 bf16_t;
typedef __attribute__((ext_vector_type(8))) __bf16 bf16x8;
typedef __attribute__((ext_vector_type(16))) float f32x16;

union BF8U { bf16x8 v; unsigned u[4]; };

// pack two f32 -> packed bf16 (a->lo, b->hi); lowers to v_cvt_pk_bf16_f32 (RNE)
__device__ inline unsigned packbf2(float a, float b) {
  union { __hip_bfloat162 v; unsigned u; } r;
  r.v = __float22bfloat162_rn(make_float2(a, b));
  return r.u;
}

__device__ inline unsigned short f2bf(float v) {
  unsigned u = __float_as_uint(v);
  return (unsigned short)((u + 0x7FFFu + ((u >> 16) & 1u)) >> 16);
}

// ---------------------------------------------------------------------------
// wcast: one-time f32 -> bf16 weight cast (q|k|v|proj|sr -> Wb). 128 blocks.
// ---------------------------------------------------------------------------
__global__ __launch_bounds__(256) void wcast(
    const float* __restrict__ qw, const float* __restrict__ kw,
    const float* __restrict__ vw, const float* __restrict__ pw,
    const float* __restrict__ srw, unsigned short* __restrict__ Wb)
{
  int e4 = (blockIdx.x * 256 + threadIdx.x) * 4;   // 0..131068, step 4
  const float* src; int idx;
  if (e4 < 16384)      { src = qw;  idx = e4; }
  else if (e4 < 32768) { src = kw;  idx = e4 - 16384; }
  else if (e4 < 49152) { src = vw;  idx = e4 - 32768; }
  else if (e4 < 65536) { src = pw;  idx = e4 - 49152; }
  else                 { src = srw; idx = e4 - 65536; }
  float4 v = *(const float4*)(src + idx);
  uint2 wv;
  wv.x = packbf2(v.x, v.y);
  wv.y = packbf2(v.z, v.w);
  *(uint2*)&Wb[e4] = wv;
}

// ---------------------------------------------------------------------------
// Fused q + (sr -> bn -> relu -> k -> v) GEMMs. A-operands staged from f32 x
// into LDS per block (transpose/im2col fused); B-operands bf16 rows of Wb.
// blocks [0,50): sr->k->v. blocks [50,250): q tile. (unchanged)
// ---------------------------------------------------------------------------
__global__ __launch_bounds__(256) void mgemm_qsrkv(
    const float* __restrict__ x, const bf16_t* __restrict__ Wb,
    const float* __restrict__ q_b, const float* __restrict__ sr_b,
    const float* __restrict__ k_b, const float* __restrict__ v_b,
    const float* __restrict__ bng, const float* __restrict__ bnb,
    const float* __restrict__ bnm, const float* __restrict__ bnv,
    unsigned short* __restrict__ Qb,
    unsigned short* __restrict__ Kp, unsigned short* __restrict__ Vp,
    float sl)
{
  __shared__ __align__(16) unsigned short xs4[32][520]; // sr A tile (im2col)
  __shared__ __align__(16) unsigned short xs[32][136];  // relu out / q A tile
  int t = threadIdx.x;
  int ln = t & 31, hf = (t >> 5) & 1, wid = t >> 6;
  int b = blockIdx.y;
  int o = wid * 32 + ln;

  if (blockIdx.x < 50) {             // ---- sr -> k -> v part ----
    int cid = blockIdx.x;
    int s0 = cid * 32;

    // Stage X4 tile: token tx, values (c,ky,kx) in im2col order c*4+ky*2+kx.
    {
      int tx = t & 31, g = t >> 5;
      int s = s0 + tx;
      int i = s / 40, j = s % 40;
      const float* xb = x + (size_t)b * DIM * NQ;
#pragma unroll
      for (int u = 0; u < 32; ++u) {
        int idx2 = g * 32 + u;       // c*2 + ky
        int c = idx2 >> 1, ky = idx2 & 1;
        const float* src = xb + (size_t)c * NQ + (2 * i + ky) * 80 + 2 * j;
        float2 vv = *(const float2*)src;             // kx = 0,1 contiguous
        *(unsigned*)&xs4[tx][c * 4 + ky * 2] = packbf2(vv.x, vv.y);
      }
    }
    __syncthreads();

    // sr GEMM: K = 512 off the LDS tile; B rows from Wb (bf16).
    const unsigned short* arow = &xs4[ln][hf * 8];
    const bf16_t* brow = &Wb[65536 + (size_t)o * 512 + hf * 8];
    f32x16 acc = {};
#pragma unroll 8
    for (int c0 = 0; c0 < 512; c0 += 16) {
      bf16x8 af = *(const bf16x8*)&arow[c0];
      bf16x8 bf = *(const bf16x8*)&brow[c0];
      acc = __builtin_amdgcn_mfma_f32_32x32x16_bf16(af, bf, acc, 0, 0, 0);
    }
    float bv = sr_b[o];
    float inv = bng[o] / sqrtf(bnv[o] + BN_EPS);
    float b2 = bnb[o] - bnm[o] * inv;
#pragma unroll
    for (int g = 0; g < 4; ++g)
#pragma unroll
      for (int jj = 0; jj < 4; ++jj) {
        int sr = 8 * g + 4 * hf + jj;
        xs[sr][o] = f2bf(fmaxf((acc[4 * g + jj] + bv) * inv + b2, 0.f));
      }
    __syncthreads();

    // k + v GEMMs (C=128) off the LDS tile, bf16 weight rows
    const unsigned short* ar2 = &xs[ln][hf * 8];
    const bf16_t* kbrow = &Wb[16384 + (size_t)o * DIM + hf * 8];
    const bf16_t* vbrow = &Wb[32768 + (size_t)o * DIM + hf * 8];
    f32x16 ka = {}, va = {};
#pragma unroll
    for (int c0 = 0; c0 < 128; c0 += 16) {
      bf16x8 af = *(const bf16x8*)&ar2[c0];
      bf16x8 kb = *(const bf16x8*)&kbrow[c0];
      bf16x8 vb = *(const bf16x8*)&vbrow[c0];
      ka = __builtin_amdgcn_mfma_f32_32x32x16_bf16(af, kb, ka, 0, 0, 0);
      va = __builtin_amdgcn_mfma_f32_32x32x16_bf16(af, vb, va, 0, 0, 0);
    }
    int hloc = o >> 4, d = o & 15;
    {
      float kb2 = k_b[o];
      size_t CB = (((size_t)b * HEADS + hloc) * NC + cid) * 512;
#pragma unroll
      for (int g = 0; g < 4; ++g)
#pragma unroll
        for (int jj = 0; jj < 4; ++jj) {
          int sl2 = 8 * g + 4 * hf + jj;
          Kp[CB + sl2 * 16 + d] = f2bf(ka[4 * g + jj] + kb2);
        }
    }
    {
      float vb2 = v_b[o];
      size_t CB = (((size_t)b * HEADS + hloc) * NC + cid) * 1024;
      uint4 w0, w1;
      w0.x = packbf2(va[0] + vb2, va[1] + vb2);
      w0.y = packbf2(va[2] + vb2, va[3] + vb2);
      w0.z = packbf2(va[4] + vb2, va[5] + vb2);
      w0.w = packbf2(va[6] + vb2, va[7] + vb2);
      w1.x = packbf2(va[8] + vb2, va[9] + vb2);
      w1.y = packbf2(va[10] + vb2, va[11] + vb2);
      w1.z = packbf2(va[12] + vb2, va[13] + vb2);
      w1.w = packbf2(va[14] + vb2, va[15] + vb2);
      *(uint4*)&Vp[CB + d * 16 + hf * 8] = w0;       // va block
      *(uint4*)&Vp[CB + 512 + d * 16 + hf * 8] = w1; // vb block
    }
    // Vp lane-16 (denominator) rows for this (b, chunk), all 8 heads
    {
      int hh = t >> 5, pos = t & 31;
      size_t addr = (((size_t)b * HEADS + hh) * NC + cid) * 1024 + 256 +
                    ((pos & 16) ? 512 : 0) + (pos & 15);
      Vp[addr] = 0x3F80;               // 1.0 bf16
    }
  } else {                           // ---- q part (C = 128) ----
    int s0 = (blockIdx.x - 50) * 32;

    // Stage 32-token x 128-channel bf16 tile, token-major (coalesced reads).
    {
      int tx = t & 31, cg = t >> 5;
      const float* xb = x + (size_t)b * DIM * NQ + s0 + tx;
#pragma unroll
      for (int it = 0; it < 8; ++it) {
        int c = 2 * cg + 16 * it;
        float a0 = xb[(size_t)c * NQ];
        float a1 = xb[(size_t)(c + 1) * NQ];
        *(unsigned*)&xs[tx][c] = packbf2(a0, a1);
      }
    }
    __syncthreads();

    const unsigned short* arow = &xs[ln][hf * 8];
    const bf16_t* brow = &Wb[(size_t)o * DIM + hf * 8];
    f32x16 acc = {};
#pragma unroll
    for (int c0 = 0; c0 < 128; c0 += 16) {
      bf16x8 af = *(const bf16x8*)&arow[c0];
      bf16x8 bf = *(const bf16x8*)&brow[c0];
      acc = __builtin_amdgcn_mfma_f32_32x32x16_bf16(af, bf, acc, 0, 0, 0);
    }
    float bv = q_b[o];
#pragma unroll
    for (int g = 0; g < 4; ++g)
#pragma unroll
      for (int jj = 0; jj < 4; ++jj) {
        int sq = s0 + 8 * g + 4 * hf + jj;
        Qb[((size_t)b * NQ + sq) * DIM + o] = f2bf((acc[4 * g + jj] + bv) * sl);
      }
  }
}

// ---------------------------------------------------------------------------
// MFMA attention, round-10: R9 structure (full softmax per block, 4-wave
// stride-4 chunk split, LDS cross-wave reduce, fused normalize) + one-iter
// NAMED-SLOT PREFETCH. R9 had zero prefetch (kf loaded then immediately
// consumed -> full L2 latency per iter unless TLP covers it); R7 showed
// prefetch without TLP is useless; this combines both: load->use distance =
// 1 full iteration AND ~5-6 waves/SIMD resident (+24 regs for the slots).
// grid (200, 8, 2). block 256.
// ---------------------------------------------------------------------------
__global__ __launch_bounds__(256) void attn_full(
    const bf16_t* __restrict__ Qb, const bf16_t* __restrict__ Kp,
    const bf16_t* __restrict__ Vp, unsigned short* __restrict__ Pb)
{
  __shared__ float R[4][9][64];

  const int t = threadIdx.x;
  const int ln = t & 31, hf = (t >> 5) & 1, wid = t >> 6;
  const int h = blockIdx.y;
  const int b = blockIdx.z;
  const int q0 = blockIdx.x * 32;

  bf16x8 qf = *(const bf16x8*)&Qb[((size_t)b * NQ + q0 + ln) * DIM + h * 16 + hf * 8];
  const int bh = b * HEADS + h;
  const bf16_t* kc = &Kp[(size_t)bh * NC * 512 + ln * 16 + hf * 8];
  const bf16_t* vc = &Vp[(size_t)bh * NC * 1024 + ln * 16 + hf * 8];

  f32x16 acc = {};
  const f32x16 zero = {};

  // prologue: current slot <- chunk wid
  bf16x8 kA  = *(const bf16x8*)(kc + (size_t)wid * 512);
  bf16x8 vaA = *(const bf16x8*)(vc + (size_t)wid * 1024);
  bf16x8 vbA = *(const bf16x8*)(vc + (size_t)wid * 1024 + 512);

  for (int c = wid; c < NC; c += 4) {
    int cn = (c + 4 < NC) ? c + 4 : c;   // clamp: tail reloads current (safe)
    bf16x8 kN  = *(const bf16x8*)(kc + (size_t)cn * 512);
    bf16x8 vaN = *(const bf16x8*)(vc + (size_t)cn * 1024);
    bf16x8 vbN = *(const bf16x8*)(vc + (size_t)cn * 1024 + 512);

    f32x16 S = __builtin_amdgcn_mfma_f32_32x32x16_bf16(kA, qf, zero, 0, 0, 0);
    BF8U f0, f1;
#pragma unroll
    for (int j = 0; j < 4; ++j) {
      f0.u[j] = packbf2(__builtin_amdgcn_exp2f(S[2 * j]),
                        __builtin_amdgcn_exp2f(S[2 * j + 1]));
      f1.u[j] = packbf2(__builtin_amdgcn_exp2f(S[8 + 2 * j]),
                        __builtin_amdgcn_exp2f(S[9 + 2 * j]));
    }
    acc = __builtin_amdgcn_mfma_f32_32x32x16_bf16(vaA, f0.v, acc, 0, 0, 0);
    acc = __builtin_amdgcn_mfma_f32_32x32x16_bf16(vbA, f1.v, acc, 0, 0, 0);

    kA = kN; vaA = vaN; vbA = vbN;
  }

  // cross-wave reduction (rows 0..8 only; row 8 = denominator at hf=0)
#pragma unroll
  for (int r = 0; r < 9; ++r) R[wid][r][t & 63] = acc[r];
  __syncthreads();

  if (wid == 0) {                    // wave 0: reduce + normalize + write
    int l64 = t & 63;
    float s[9];
#pragma unroll
    for (int r = 0; r < 9; ++r)
      s[r] = R[0][r][l64] + R[1][r][l64] + R[2][r][l64] + R[3][r][l64];
    float L = hf ? (R[0][8][ln] + R[1][8][ln] + R[2][8][ln] + R[3][8][ln])
                 : s[8];
    float inv = __builtin_amdgcn_rcpf(L);

    // s[0..3] -> d = 4*hf+0..3 ; s[4..7] -> d = 8+4*hf+0..3 (col q = ln)
    unsigned short* prow =
        &Pb[(size_t)b * (NQ * DIM) + (size_t)(q0 + ln) * DIM + h * 16 + 4 * hf];
    uint2 w0, w1;
    w0.x = packbf2(s[0] * inv, s[1] * inv);
    w0.y = packbf2(s[2] * inv, s[3] * inv);
    w1.x = packbf2(s[4] * inv, s[5] * inv);
    w1.y = packbf2(s[6] * inv, s[7] * inv);
    *(uint2*)&prow[0] = w0;
    *(uint2*)&prow[8] = w1;
  }
}

// ---------------------------------------------------------------------------
// proj: reference scramble + proj GEMM (flat transpose: A[s][c] =
// Pb[flat = c*NQ + s]). LDS gather stage (u32 loads = 2 tokens/lane), then
// pure GEMM off the already-normalized Pb. grid (200,2), blk 256.
// ---------------------------------------------------------------------------
__global__ __launch_bounds__(256) void proj(
    const unsigned short* __restrict__ Pb, const bf16_t* __restrict__ Wb,
    const float* __restrict__ p_b, float* __restrict__ Out)
{
  __shared__ __align__(16) unsigned short As[32][136];
  int t = threadIdx.x;
  int b = blockIdx.y;
  int s0 = blockIdx.x * 32;

  {
    int tp = t & 15, cg = t >> 4;          // token pair, 16 channel groups
    const unsigned short* pbase = Pb + (size_t)b * (NQ * DIM);
#pragma unroll
    for (int it = 0; it < 8; ++it) {
      int c = cg * 8 + it;
      int f = c * NQ + s0 + 2 * tp;        // flat att index (even -> aligned)
      unsigned u = *(const unsigned*)&pbase[f];
      As[2 * tp][c]     = (unsigned short)(u & 0xFFFFu);
      As[2 * tp + 1][c] = (unsigned short)(u >> 16);
    }
  }
  __syncthreads();

  int ln = t & 31, hf = (t >> 5) & 1, wid = t >> 6;
  int o = wid * 32 + ln;
  const bf16_t* brow = &Wb[49152 + (size_t)o * DIM + hf * 8];
  const unsigned short* arow = &As[ln][hf * 8];
  f32x16 acc = {};
#pragma unroll
  for (int c0 = 0; c0 < 128; c0 += 16) {
    bf16x8 af = *(const bf16x8*)&arow[c0];
    bf16x8 bf = *(const bf16x8*)&brow[c0];
    acc = __builtin_amdgcn_mfma_f32_32x32x16_bf16(af, bf, acc, 0, 0, 0);
  }
  float bv = p_b[o];
  float* obase = &Out[((size_t)b * DIM + o) * NQ + s0 + 4 * hf];
#pragma unroll
  for (int g = 0; g < 4; ++g) {
    float4 r;
    r.x = acc[4 * g + 0] + bv; r.y = acc[4 * g + 1] + bv;
    r.z = acc[4 * g + 2] + bv; r.w = acc[4 * g + 3] + bv;
    *(float4*)&obase[8 * g] = r;
  }
}

// ---------------------------------------------------------------------------
extern "C" void kernel_launch(void* const* d_in, const int* in_sizes, int n_in,
                              void* d_out, int out_size, void* d_ws, size_t ws_size,
                              hipStream_t stream)
{
  const float* x    = (const float*)d_in[0];
  const float* q_w  = (const float*)d_in[1];
  const float* q_b  = (const float*)d_in[2];
  const float* k_w  = (const float*)d_in[3];
  const float* k_b  = (const float*)d_in[4];
  const float* v_w  = (const float*)d_in[5];
  const float* v_b  = (const float*)d_in[6];
  const float* sr_w = (const float*)d_in[7];
  const float* sr_b = (const float*)d_in[8];
  const float* bng  = (const float*)d_in[9];
  const float* bnb  = (const float*)d_in[10];
  const float* bnm  = (const float*)d_in[11];
  const float* bnv  = (const float*)d_in[12];
  const float* p_w  = (const float*)d_in[13];
  const float* p_b  = (const float*)d_in[14];
  float* out = (float*)d_out;

  float* ws = (float*)d_ws;
  // f32-slot layout, no aliasing:
  bf16_t* Qb   = (bf16_t*)(ws);             // [0, 819200)
  bf16_t* Kp   = (bf16_t*)(ws + 819200);    // [819200, 1024000)
  bf16_t* Vp   = (bf16_t*)(ws + 1024000);   // [1024000, 1433600)
  bf16_t* Pb   = (bf16_t*)(ws + 1433600);   // [1433600, 2252800) 2 slices
  bf16_t* Wb   = (bf16_t*)(ws + 2252800);   // [2252800, 2318336)

  const float sl = 0.25f * LOG2E;  // SCALE * log2(e) folded into Q

  // 1. one-time weight cast (tiny)
  wcast<<<dim3(128), dim3(256), 0, stream>>>(
      q_w, k_w, v_w, p_w, sr_w, (unsigned short*)Wb);

  // 2. fused q + sr->k->v from f32 x (LDS-staged A) + bf16 Wb rows
  mgemm_qsrkv<<<dim3(250, NBATCH), dim3(256), 0, stream>>>(
      x, Wb, q_b, sr_b, k_b, v_b, bng, bnb, bnm, bnv,
      (unsigned short*)Qb, (unsigned short*)Kp, (unsigned short*)Vp, sl);

  // 3. full attention (no kv-split) + one-iter prefetch -> final P
  attn_full<<<dim3(NQ / 32, HEADS, NBATCH), dim3(256), 0, stream>>>(
      Qb, Kp, Vp, (unsigned short*)Pb);

  // 4. scramble + proj GEMM -> f32 chan-major final output (B,128,80,80)
  proj<<<dim3(200, NBATCH), dim3(256), 0, stream>>>(
      (const unsigned short*)Pb, Wb, p_b, out);
}